// Round 14
// baseline (158.515 us; speedup 1.0000x reference)
//
#include <hip/hip_runtime.h>
#include <hip/hip_bf16.h>

#define BB 8
#define TT 256
#define DIN 64
#define DD 128

__device__ __forceinline__ float gelu_tanh(float x) {
  float x3 = x * x * x;
  return 0.5f * x * (1.0f + tanhf(0.7978845608028654f * (x + 0.044715f * x3)));
}
__device__ __forceinline__ float sigmoidf(float x) {
  return 1.0f / (1.0f + __expf(-x));
}

template <typename T> __device__ __forceinline__ float getv(const void* p, int i);
template <> __device__ __forceinline__ float getv<float>(const void* p, int i) {
  return ((const float*)p)[i];
}
template <> __device__ __forceinline__ float getv<__hip_bfloat16>(const void* p, int i) {
  return __bfloat162float(((const __hip_bfloat16*)p)[i]);
}

// 16B weight chunk -> VEC fma's. VEC=8 (bf16) / 4 (fp32). (r9/r10-validated)
template <typename T>
__device__ __forceinline__ void fmaV(float* acc, uint4 wv, float fc);
template <>
__device__ __forceinline__ void fmaV<float>(float* acc, uint4 wv, float fc) {
  acc[0] += fc * __uint_as_float(wv.x);
  acc[1] += fc * __uint_as_float(wv.y);
  acc[2] += fc * __uint_as_float(wv.z);
  acc[3] += fc * __uint_as_float(wv.w);
}
template <>
__device__ __forceinline__ void fmaV<__hip_bfloat16>(float* acc, uint4 wv,
                                                     float fc) {
  const unsigned int u0 = wv.x, u1 = wv.y, u2 = wv.z, u3 = wv.w;
  acc[0] += fc * __uint_as_float(u0 << 16);
  acc[1] += fc * __uint_as_float(u0 & 0xffff0000u);
  acc[2] += fc * __uint_as_float(u1 << 16);
  acc[3] += fc * __uint_as_float(u1 & 0xffff0000u);
  acc[4] += fc * __uint_as_float(u2 << 16);
  acc[5] += fc * __uint_as_float(u2 & 0xffff0000u);
  acc[6] += fc * __uint_as_float(u3 << 16);
  acc[7] += fc * __uint_as_float(u3 & 0xffff0000u);
}

// DPP-based add from a statically-controlled source lane. All-VALU.
// Harness-validated correct in rounds 1/3/4/5/6/7/8/9/10/11/12.
template <int CTRL>
__device__ __forceinline__ float dpp_add(float x) {
  int s = __builtin_amdgcn_update_dpp(0, __float_as_int(x), CTRL, 0xF, 0xF, true);
  return x + __int_as_float(s);
}

// Sum across a 16-lane row.
__device__ __forceinline__ float rowsum16(float p) {
  p = dpp_add<0xB1>(p);   // quad_perm [1,0,3,2]  (xor 1)
  p = dpp_add<0x4E>(p);   // quad_perm [2,3,0,1]  (xor 2)
  p = dpp_add<0x124>(p);  // row_ror:4
  p = dpp_add<0x128>(p);  // row_ror:8
  return p;
}

// Async global->LDS, 16B per lane. (r6-validated)
__device__ __forceinline__ void gload_lds16(const void* g, void* l) {
  __builtin_amdgcn_global_load_lds(
      (const __attribute__((address_space(1))) void*)g,
      (__attribute__((address_space(3))) void*)l, 16, 0, 0);
}

// Per-thread dtype test on one u16 sample (bf16-decode plausibility).
// bf16 N(0,1) ~99.9% good, fp32 bitstream ~55% -> >13 sigma separation.
__device__ __forceinline__ int dtype_good(const unsigned short* u, int idx) {
  unsigned int bits = ((unsigned int)u[idx]) << 16;
  float f = __uint_as_float(bits);
  float a = fabsf(f);
  return (a == 0.0f || (a > 1e-4f && a < 100.0f)) ? 1 : 0;
}

// ---------------------------------------------------------------------------
// k1: per (b,t) row: f = gelu(x@W_b+b_b); k=f@Wk; v=f@Wv; meta scalars.
// (r9 vectorized structure, validated; unchanged.)
// ---------------------------------------------------------------------------
template <typename T>
__device__ void k1_body(const void* x, const void* W_b, const void* b_b,
                        const void* Wk, const void* Wv, const void* Wq,
                        const void* W_m, const void* b_m,
                        float* kout, float* vout, float* scal4,
                        float* q_last, float* f_last) {
  constexpr int VEC = (sizeof(T) == 2) ? 8 : 4;  // weights per 16B
  constexpr int OC = DD / VEC;                   // o-chunks: 16 / 32
  constexpr int SPL = 128 / OC;                  // c-splits: 8 / 4
  const int row = blockIdx.x;          // 0..2047
  const int b = row >> 8, t = row & 255;
  const int tid = threadIdx.x;         // 0..127
  const int oc = tid % OC, s = tid / OC;

  __shared__ float xs[DIN];
  __shared__ float fs[DD];
  __shared__ float partA[128 * DD / 16];  // SPL*DD <= 1024 floats
  __shared__ float partB[128 * DD / 16];

  if (tid < DIN) xs[tid] = getv<T>(x, row * DIN + tid);
  __syncthreads();

  float acc[VEC];

#define GEMV_PART(Wp, SRC, R, PART)                                          \
  {                                                                          \
    _Pragma("unroll") for (int j = 0; j < VEC; ++j) acc[j] = 0.0f;           \
    constexpr int rps = (R) / SPL;                                           \
    _Pragma("unroll 4") for (int cc = 0; cc < rps; ++cc) {                   \
      const int c = s * rps + cc;                                            \
      const uint4 wv =                                                       \
          *(const uint4*)((const T*)(Wp) + (size_t)c * DD + oc * VEC);       \
      fmaV<T>(acc, wv, (SRC)[c]);                                            \
    }                                                                        \
    _Pragma("unroll") for (int j = 0; j < VEC; ++j)                          \
        (PART)[s * DD + oc * VEC + j] = acc[j];                              \
  }

  // f = gelu(x @ W_b + b_b)
  GEMV_PART(W_b, xs, DIN, partA);
  __syncthreads();
  if (tid < DD) {
    float a = getv<T>(b_b, tid);
#pragma unroll
    for (int ss = 0; ss < SPL; ++ss) a += partA[ss * DD + tid];
    fs[tid] = gelu_tanh(a);
  }
  __syncthreads();

  // k = f @ Wk ; v = f @ Wv  (independent part buffers, one sync)
  GEMV_PART(Wk, fs, DD, partA);
  GEMV_PART(Wv, fs, DD, partB);
  __syncthreads();
  if (tid < DD) {
    float ak = 0.0f, av = 0.0f;
#pragma unroll
    for (int ss = 0; ss < SPL; ++ss) {
      ak += partA[ss * DD + tid];
      av += partB[ss * DD + tid];
    }
    kout[row * DD + tid] = ak;
    vout[row * DD + tid] = av;
  }

  // meta = sigmoid(f @ W_m + b_m): wave-parallel (wave 0), reads fs only
  if (tid < 64) {
    float a3[3];
#pragma unroll
    for (int j = 0; j < 3; ++j) {
      float pj = fs[tid] * getv<T>(W_m, tid * 3 + j) +
                 fs[tid + 64] * getv<T>(W_m, (tid + 64) * 3 + j);
      pj = rowsum16(pj);
      pj += __shfl_xor(pj, 16);
      pj += __shfl_xor(pj, 32);
      a3[j] = pj;
    }
    if (tid == 0) {
      scal4[row * 4 + 0] = 0.01f * sigmoidf(a3[0] + getv<T>(b_m, 0));
      scal4[row * 4 + 1] = sigmoidf(a3[1] + getv<T>(b_m, 1));
      scal4[row * 4 + 2] = 0.1f * sigmoidf(a3[2] + getv<T>(b_m, 2));
      scal4[row * 4 + 3] = 0.0f;
    }
  }

  // q & f kept only for t = T-1 (block-uniform branch -> syncthreads safe)
  if (t == TT - 1) {
    __syncthreads();
    GEMV_PART(Wq, fs, DD, partA);
    __syncthreads();
    if (tid < DD) {
      float aq = 0.0f;
#pragma unroll
      for (int ss = 0; ss < SPL; ++ss) aq += partA[ss * DD + tid];
      q_last[b * DD + tid] = aq;
      f_last[b * DD + tid] = fs[tid];
    }
  }
#undef GEMV_PART
}

__global__ __launch_bounds__(128) void k1_kern(
    const void* x, const void* W_b, const void* b_b, const void* Wk,
    const void* Wv, const void* Wq, const void* W_m, const void* b_m,
    float* kout, float* vout, float* scal4, float* q_last, float* f_last) {
  __shared__ int gcnt[2];
  {
    const int tid = threadIdx.x;
    const unsigned short* u = (const unsigned short*)x;
    int good = 0;
#pragma unroll
    for (int j = 0; j < 16; ++j) good += dtype_good(u, j * 128 + tid);
    float gf = (float)good;
    gf = rowsum16(gf);
    gf += __shfl_xor(gf, 16);
    gf += __shfl_xor(gf, 32);
    if ((tid & 63) == 0) gcnt[tid >> 6] = (int)(gf + 0.5f);
  }
  __syncthreads();
  const bool isbf16 = (gcnt[0] + gcnt[1] >= 1536);
  __syncthreads();  // gcnt re-use safety before body's LDS writes

  if (isbf16)
    k1_body<__hip_bfloat16>(x, W_b, b_b, Wk, Wv, Wq, W_m, b_m, kout, vout,
                            scal4, q_last, f_last);
  else
    k1_body<float>(x, W_b, b_b, Wk, Wv, Wq, W_m, b_m, kout, vout, scal4,
                   q_last, f_last);
}

// ---------------------------------------------------------------------------
// k2: the scan — r13 ALGEBRAIC LOOKAHEAD (resubmitted r14; r13 bench was an
// infra failure, audit found no kernel-side hazard).
//
// r12's null (prefetch pinning didn't help) + r10 PMC (active-SIMD busy only
// ~30% at 1 wave/SIMD) => per-step cost is the serial dependency chain:
// dot -> rowsum16(4 DPP) -> err -> c -> S -> M -> next dot, all latencies
// exposed (in-order issue, no TLP possible: 1024 chains = 1 wave/SIMD max).
//
// Transform: p_t = M_{t-1}.k_t
//          = am_{t-1}*(M_{t-2}.k_t) + et_{t-1}*(S_{t-2}.k_t)
//            - c_{t-1}*(k_{t-1}.k_t)
// The three dots (dm,ds,kk) + their rowsums depend only on 2-step-old state
// and raw data -> computed one iteration EARLY, off the chain. Per-step
// chain shrinks to c_{t-1} -> p (3 fma) -> err -> c_t  (~5 ops).
// Schedule per iteration j: phase1 = dots for step j (uses M,S = state
// before this iteration's update, kPrev=k_{j-1}); phase2 = scalars for step
// j-1 (consumes last iteration's dots, am/et from sc_{j-2}, c_{j-2});
// phase3 = M/S update for step j-1. Zero-init kPrev/DM/DS/KK/cP/sc2 makes
// j=0,1 exact (no 0*garbage). Identical math, reassociated.
// Staging: r6 chunk double-buffer; fragment map: r11 conflict-free.
// ---------------------------------------------------------------------------
__global__ __launch_bounds__(64) void k2_scan(
    const float* __restrict__ kbuf, const float* __restrict__ vbuf,
    const float* __restrict__ scal, const float* __restrict__ q_last,
    float* __restrict__ m_last) {
  const int tid = threadIdx.x;         // 0..63
  const int g = tid & 15;
  const int cidx = tid >> 4;           // chain-in-block 0..3
  const int chain = blockIdx.x * 4 + cidx;
  const int b = chain >> 7;
  const int i = chain & 127;
  const int i0 = (blockIdx.x * 4) & 127;  // first chain's column

  __shared__ float kl[2][32 * DD];     // 2 x 16KB k chunks (32 t-rows each)
  __shared__ float vl[TT * 4];         // v[t][c] for this block's 4 chains
  __shared__ float4 scl[TT];           // (theta,eta,alpha,0) per t

  const float* kslice = kbuf + (size_t)b * TT * DD;
  const float* vslice = vbuf + (size_t)b * TT * DD;

  for (int idx = tid; idx < TT * 4; idx += 64)
    vl[idx] = vslice[(idx >> 2) * DD + i0 + (idx & 3)];
  const float4* sp4 = (const float4*)scal + b * TT;
  for (int idx = tid; idx < TT; idx += 64) scl[idx] = sp4[idx];

#define K2_GLL(CH, BUF)                                                      \
  {                                                                          \
    const float* gs = kslice + (CH) * 32 * DD + tid * 4;                     \
    _Pragma("unroll") for (int j = 0; j < 16; ++j)                           \
        gload_lds16(gs + j * 256, &kl[BUF][j * 256]);                        \
  }
  K2_GLL(0, 0);

  // scan state (zero-init = M_{-1}, S_{-1})
  float4 Ma = {0, 0, 0, 0}, Mb = {0, 0, 0, 0};
  float4 Sa = {0, 0, 0, 0}, Sb = {0, 0, 0, 0};
  // pipeline state
  float4 kpa = {0, 0, 0, 0}, kpb = {0, 0, 0, 0};  // k_{j-1} (0 -> kk_0 = 0)
  float DMc = 0.0f, DSc = 0.0f, KKc = 0.0f;       // dots for step j-1
  float4 sc1 = {0, 0, 0, 0}, sc2 = {0, 0, 0, 0};  // sc_{j-1}, sc_{j-2}
  float v1 = 0.0f;                                // v_{j-1}
  float cP = 0.0f;                                // c_{j-2}

  // prologue: v_0, sc_0 (consumed at iteration j=1 as step-0 scalars)
  v1 = vl[cidx];
  sc1 = scl[0];

#define K2_PHASE23()                                                         \
  {                                                                          \
    const float am2 = 1.0f - sc2.z, et2 = sc2.y;                             \
    const float p = am2 * DMc + et2 * DSc - cP * KKc;                        \
    const float err = p - v1;                                                \
    const float c = sc1.x * err;                                             \
    const float et1 = sc1.y, am1 = 1.0f - sc1.z;                             \
    Sa.x = et1 * Sa.x - c * kpa.x;  Ma.x = am1 * Ma.x + Sa.x;                \
    Sa.y = et1 * Sa.y - c * kpa.y;  Ma.y = am1 * Ma.y + Sa.y;                \
    Sa.z = et1 * Sa.z - c * kpa.z;  Ma.z = am1 * Ma.z + Sa.z;                \
    Sa.w = et1 * Sa.w - c * kpa.w;  Ma.w = am1 * Ma.w + Sa.w;                \
    Sb.x = et1 * Sb.x - c * kpb.x;  Mb.x = am1 * Mb.x + Sb.x;                \
    Sb.y = et1 * Sb.y - c * kpb.y;  Mb.y = am1 * Mb.y + Sb.y;                \
    Sb.z = et1 * Sb.z - c * kpb.z;  Mb.z = am1 * Mb.z + Sb.z;                \
    Sb.w = et1 * Sb.w - c * kpb.w;  Mb.w = am1 * Mb.w + Sb.w;                \
    cP = c;                                                                  \
  }

  for (int ch = 0; ch < 8; ++ch) {
    asm volatile("s_waitcnt vmcnt(0) lgkmcnt(0)" ::: "memory");
    if (ch < 7) K2_GLL(ch + 1, (ch + 1) & 1);

    const float* kc = &kl[ch & 1][0];
    const int tbase = ch * 32;

#pragma unroll
    for (int tt = 0; tt < 32; ++tt) {
      const int j = tbase + tt;
      // ---- phase1(j): dots vs M_{j-2},S_{j-2} (pre-update M,S), kPrev ----
      float4 ka = *(const float4*)(kc + tt * DD + g * 4);
      float4 kb = *(const float4*)(kc + tt * DD + 64 + g * 4);
      float dm = (Ma.x * ka.x + Ma.y * ka.y) + (Ma.z * ka.z + Ma.w * ka.w) +
                 (Mb.x * kb.x + Mb.y * kb.y) + (Mb.z * kb.z + Mb.w * kb.w);
      float ds = (Sa.x * ka.x + Sa.y * ka.y) + (Sa.z * ka.z + Sa.w * ka.w) +
                 (Sb.x * kb.x + Sb.y * kb.y) + (Sb.z * kb.z + Sb.w * kb.w);
      float kk = (kpa.x * ka.x + kpa.y * ka.y) + (kpa.z * ka.z + kpa.w * ka.w) +
                 (kpb.x * kb.x + kpb.y * kb.y) + (kpb.z * kb.z + kpb.w * kb.w);
      dm = rowsum16(dm);
      ds = rowsum16(ds);
      kk = rowsum16(kk);
      float vCur = vl[j * 4 + cidx];
      float4 scCur = scl[j];

      // ---- phase2+3 (step j-1); tt>0 is compile-time, tt==0 tests ch ----
      if (tt > 0) {
        K2_PHASE23();
      } else if (ch > 0) {
        K2_PHASE23();
      }

      // ---- rotate pipeline registers (renamed away by full unroll) ----
      DMc = dm; DSc = ds; KKc = kk;
      sc2 = sc1; sc1 = scCur; v1 = vCur;
      kpa = ka; kpb = kb;
    }
  }
  // epilogue: step TT-1
  K2_PHASE23();
#undef K2_PHASE23
#undef K2_GLL

  // q dot with final M (r11 conflict-free fragment map)
  const float* qb0 = q_last + b * DD;
  float4 qa = *(const float4*)(qb0 + g * 4);
  float4 qb = *(const float4*)(qb0 + 64 + g * 4);
  float p = (Ma.x * qa.x + Ma.y * qa.y) + (Ma.z * qa.z + Ma.w * qa.w) +
            (Mb.x * qb.x + Mb.y * qb.y) + (Mb.z * qb.z + Mb.w * qb.w);
  p = rowsum16(p);
  if (g == 0) m_last[b * DD + i] = p;
}

// ---------------------------------------------------------------------------
// k3: fused head (r10 vectorized structure, validated; unchanged).
// 88 blocks (8 b x 11 j-chunks) x 256 threads.
// ---------------------------------------------------------------------------
template <typename T>
__device__ void k3_body(const float* f_last, const float* m_last,
                        const void* W_f, const void* b_f, const void* W1,
                        const void* b1, const void* g1, const void* be1,
                        const void* W2, const void* b2, void* out) {
  constexpr int VEC = (sizeof(T) == 2) ? 8 : 4;  // weights per 16B
  constexpr int OC = DD / VEC;                   // 16 / 32
  constexpr int SPL = 256 / OC;                  // 16 / 8
  const int b = blockIdx.x / 11;
  const int jc = blockIdx.x % 11;
  const int tid = threadIdx.x;        // 0..255
  const int oc = tid % OC, s = tid / OC;

  __shared__ float fm[2 * DD];
  __shared__ float part[2048];        // max(SPL*DD, SPL2*64) floats
  __shared__ float fused[DD];
  __shared__ float tmp[DD];
  __shared__ float h[DD];
  __shared__ float smu, srs;

  if (tid < 2 * DD)
    fm[tid] = (tid < DD) ? f_last[b * DD + tid] : m_last[b * DD + tid - DD];
  __syncthreads();

  float acc[VEC];

  // gate gemv: rows 2*DD=256, split SPL ways
  {
#pragma unroll
    for (int j = 0; j < VEC; ++j) acc[j] = 0.0f;
    constexpr int rps = 256 / SPL;  // 16 / 32
#pragma unroll 4
    for (int cc = 0; cc < rps; ++cc) {
      const int c = s * rps + cc;
      const uint4 wv =
          *(const uint4*)((const T*)W_f + (size_t)c * DD + oc * VEC);
      fmaV<T>(acc, wv, fm[c]);
    }
#pragma unroll
    for (int j = 0; j < VEC; ++j) part[s * DD + oc * VEC + j] = acc[j];
  }
  __syncthreads();
  if (tid < DD) {
    float a = getv<T>(b_f, tid);
#pragma unroll
    for (int ss = 0; ss < SPL; ++ss) a += part[ss * DD + tid];
    float gte = sigmoidf(a);
    fused[tid] = fm[tid] * gte + fm[DD + tid] * (1.0f - gte);
  }
  __syncthreads();

  // W1 gemv: rows DD=128
  {
#pragma unroll
    for (int j = 0; j < VEC; ++j) acc[j] = 0.0f;
    constexpr int rps = DD / SPL;  // 8 / 16
#pragma unroll 4
    for (int cc = 0; cc < rps; ++cc) {
      const int c = s * rps + cc;
      const uint4 wv =
          *(const uint4*)((const T*)W1 + (size_t)c * DD + oc * VEC);
      fmaV<T>(acc, wv, fused[c]);
    }
#pragma unroll
    for (int j = 0; j < VEC; ++j) part[s * DD + oc * VEC + j] = acc[j];
  }
  __syncthreads();
  if (tid < DD) {
    float a = getv<T>(b1, tid);
#pragma unroll
    for (int ss = 0; ss < SPL; ++ss) a += part[ss * DD + tid];
    tmp[tid] = a;
  }
  __syncthreads();

  // LN stats: wave-parallel reduce over 128 elems (first wave only)
  if (tid < 64) {
    float x0 = tmp[tid], x1 = tmp[tid + 64];
    float sm = x0 + x1;
    float sq = x0 * x0 + x1 * x1;
    sm = rowsum16(sm);
    sq = rowsum16(sq);
    sm += __shfl_xor(sm, 16); sq += __shfl_xor(sq, 16);
    sm += __shfl_xor(sm, 32); sq += __shfl_xor(sq, 32);
    if (tid == 0) {
      float mu = sm / (float)DD;
      smu = mu;
      srs = rsqrtf(sq / (float)DD - mu * mu + 1e-5f);
    }
  }
  __syncthreads();

  if (tid < DD)
    h[tid] = gelu_tanh((tmp[tid] - smu) * srs * getv<T>(g1, tid) +
                       getv<T>(be1, tid));
  __syncthreads();

  // W2 chunk gemv: 64 j's tiled as (jv x VEC), c split SPL2 ways
  {
    constexpr int NJ = 64 / VEC;     // 8 / 16
    constexpr int SPL2 = 256 / NJ;   // 32 / 16
    constexpr int rps2 = DD / SPL2;  // 4 / 8
    const int jv = tid % NJ, s2 = tid / NJ;
    const int jbase = jc * 64 + jv * VEC;
#pragma unroll
    for (int j = 0; j < VEC; ++j) acc[j] = 0.0f;
    if (jbase < 672) {  // jc=10 tail guard (uniform per thread)
#pragma unroll
      for (int cc = 0; cc < rps2; ++cc) {
        const int c = s2 * rps2 + cc;
        const uint4 wv = *(const uint4*)((const T*)W2 + (size_t)c * 672 + jbase);
        fmaV<T>(acc, wv, h[c]);
      }
    }
#pragma unroll
    for (int j = 0; j < VEC; ++j) part[s2 * 64 + jv * VEC + j] = acc[j];
    __syncthreads();

    const int j = jc * 64 + tid;
    if (tid < 64 && j < 672) {
      float r = getv<T>(b2, j);
#pragma unroll
      for (int ss = 0; ss < SPL2; ++ss) r += part[ss * 64 + tid];
      if (sizeof(T) == 2)
        ((__hip_bfloat16*)out)[b * 672 + j] = __float2bfloat16(r);
      else
        ((float*)out)[b * 672 + j] = r;
    }
  }
}

__global__ __launch_bounds__(256) void k3_kern(
    const void* x, const float* f_last, const float* m_last, const void* W_f,
    const void* b_f, const void* W1, const void* b1, const void* g1,
    const void* be1, const void* W2, const void* b2, void* out) {
  __shared__ int gcnt[4];
  {
    const int tid = threadIdx.x;
    const unsigned short* u = (const unsigned short*)x;
    int good = 0;
#pragma unroll
    for (int j = 0; j < 8; ++j) good += dtype_good(u, j * 256 + tid);
    float gf = (float)good;
    gf = rowsum16(gf);
    gf += __shfl_xor(gf, 16);
    gf += __shfl_xor(gf, 32);
    if ((tid & 63) == 0) gcnt[tid >> 6] = (int)(gf + 0.5f);
  }
  __syncthreads();
  const bool isbf16 = (gcnt[0] + gcnt[1] + gcnt[2] + gcnt[3] >= 1536);
  __syncthreads();

  if (isbf16)
    k3_body<__hip_bfloat16>(f_last, m_last, W_f, b_f, W1, b1, g1, be1, W2, b2,
                            out);
  else
    k3_body<float>(f_last, m_last, W_f, b_f, W1, b1, g1, be1, W2, b2, out);
}

// ---------------------------------------------------------------------------
extern "C" void kernel_launch(void* const* d_in, const int* in_sizes, int n_in,
                              void* d_out, int out_size, void* d_ws,
                              size_t ws_size, hipStream_t stream) {
  const void* x   = d_in[0];
  const void* W_b = d_in[1];
  const void* b_b = d_in[2];
  const void* Wk  = d_in[3];
  const void* Wv  = d_in[4];
  const void* Wq  = d_in[5];
  const void* W_m = d_in[6];
  const void* b_m = d_in[7];
  const void* W_f = d_in[8];
  const void* b_f = d_in[9];
  const void* W1  = d_in[10];
  const void* b1  = d_in[11];
  const void* g1  = d_in[12];
  const void* be1 = d_in[13];
  const void* W2  = d_in[14];
  const void* b2  = d_in[15];

  float* w = (float*)d_ws;
  float* kbuf   = w;                    // 262144
  float* vbuf   = w + 262144;           // 262144
  float* scal4  = w + 524288;           // 8192  (theta,eta,alpha,0) per (b,t)
  float* q_last = w + 532480;           // 1024
  float* f_last = w + 533504;           // 1024
  float* m_last = w + 534528;           // 1024

  k1_kern<<<BB * TT, 128, 0, stream>>>(x, W_b, b_b, Wk, Wv, Wq, W_m, b_m,
                                       kbuf, vbuf, scal4, q_last, f_last);
  k2_scan<<<256, 64, 0, stream>>>(kbuf, vbuf, scal4, q_last, m_last);
  k3_kern<<<88, 256, 0, stream>>>(x, f_last, m_last, W_f, b_f, W1, b1, g1,
                                  be1, W2, b2, d_out);
}

// Round 15
// 145.039 us; speedup vs baseline: 1.0929x; 1.0929x over previous
//
#include <hip/hip_runtime.h>
#include <hip/hip_bf16.h>

#define BB 8
#define TT 256
#define DIN 64
#define DD 128

__device__ __forceinline__ float gelu_tanh(float x) {
  float x3 = x * x * x;
  return 0.5f * x * (1.0f + tanhf(0.7978845608028654f * (x + 0.044715f * x3)));
}
__device__ __forceinline__ float sigmoidf(float x) {
  return 1.0f / (1.0f + __expf(-x));
}

template <typename T> __device__ __forceinline__ float getv(const void* p, int i);
template <> __device__ __forceinline__ float getv<float>(const void* p, int i) {
  return ((const float*)p)[i];
}
template <> __device__ __forceinline__ float getv<__hip_bfloat16>(const void* p, int i) {
  return __bfloat162float(((const __hip_bfloat16*)p)[i]);
}

// 16B weight chunk -> VEC fma's. VEC=8 (bf16) / 4 (fp32). (r9/r10-validated)
template <typename T>
__device__ __forceinline__ void fmaV(float* acc, uint4 wv, float fc);
template <>
__device__ __forceinline__ void fmaV<float>(float* acc, uint4 wv, float fc) {
  acc[0] += fc * __uint_as_float(wv.x);
  acc[1] += fc * __uint_as_float(wv.y);
  acc[2] += fc * __uint_as_float(wv.z);
  acc[3] += fc * __uint_as_float(wv.w);
}
template <>
__device__ __forceinline__ void fmaV<__hip_bfloat16>(float* acc, uint4 wv,
                                                     float fc) {
  const unsigned int u0 = wv.x, u1 = wv.y, u2 = wv.z, u3 = wv.w;
  acc[0] += fc * __uint_as_float(u0 << 16);
  acc[1] += fc * __uint_as_float(u0 & 0xffff0000u);
  acc[2] += fc * __uint_as_float(u1 << 16);
  acc[3] += fc * __uint_as_float(u1 & 0xffff0000u);
  acc[4] += fc * __uint_as_float(u2 << 16);
  acc[5] += fc * __uint_as_float(u2 & 0xffff0000u);
  acc[6] += fc * __uint_as_float(u3 << 16);
  acc[7] += fc * __uint_as_float(u3 & 0xffff0000u);
}

// DPP-based add from a statically-controlled source lane. All-VALU.
// Harness-validated correct across rounds 1-14.
template <int CTRL>
__device__ __forceinline__ float dpp_add(float x) {
  int s = __builtin_amdgcn_update_dpp(0, __float_as_int(x), CTRL, 0xF, 0xF, true);
  return x + __int_as_float(s);
}

// Sum across a 16-lane row.
__device__ __forceinline__ float rowsum16(float p) {
  p = dpp_add<0xB1>(p);   // quad_perm [1,0,3,2]  (xor 1)
  p = dpp_add<0x4E>(p);   // quad_perm [2,3,0,1]  (xor 2)
  p = dpp_add<0x124>(p);  // row_ror:4
  p = dpp_add<0x128>(p);  // row_ror:8
  return p;
}

// Async global->LDS, 16B per lane. (r6-validated)
__device__ __forceinline__ void gload_lds16(const void* g, void* l) {
  __builtin_amdgcn_global_load_lds(
      (const __attribute__((address_space(1))) void*)g,
      (__attribute__((address_space(3))) void*)l, 16, 0, 0);
}

// Per-thread dtype test on one u16 sample (bf16-decode plausibility).
// bf16 N(0,1) ~99.9% good, fp32 bitstream ~55% -> >13 sigma separation.
__device__ __forceinline__ int dtype_good(const unsigned short* u, int idx) {
  unsigned int bits = ((unsigned int)u[idx]) << 16;
  float f = __uint_as_float(bits);
  float a = fabsf(f);
  return (a == 0.0f || (a > 1e-4f && a < 100.0f)) ? 1 : 0;
}

// ---------------------------------------------------------------------------
// k1: per (b,t) row: f = gelu(x@W_b+b_b); k=f@Wk; v=f@Wv; meta scalars.
// (r9 vectorized structure, validated.)
// ---------------------------------------------------------------------------
template <typename T>
__device__ void k1_body(const void* x, const void* W_b, const void* b_b,
                        const void* Wk, const void* Wv, const void* Wq,
                        const void* W_m, const void* b_m,
                        float* kout, float* vout, float* scal4,
                        float* q_last, float* f_last) {
  constexpr int VEC = (sizeof(T) == 2) ? 8 : 4;  // weights per 16B
  constexpr int OC = DD / VEC;                   // o-chunks: 16 / 32
  constexpr int SPL = 128 / OC;                  // c-splits: 8 / 4
  const int row = blockIdx.x;          // 0..2047
  const int b = row >> 8, t = row & 255;
  const int tid = threadIdx.x;         // 0..127
  const int oc = tid % OC, s = tid / OC;

  __shared__ float xs[DIN];
  __shared__ float fs[DD];
  __shared__ float partA[128 * DD / 16];  // SPL*DD <= 1024 floats
  __shared__ float partB[128 * DD / 16];

  if (tid < DIN) xs[tid] = getv<T>(x, row * DIN + tid);
  __syncthreads();

  float acc[VEC];

#define GEMV_PART(Wp, SRC, R, PART)                                          \
  {                                                                          \
    _Pragma("unroll") for (int j = 0; j < VEC; ++j) acc[j] = 0.0f;           \
    constexpr int rps = (R) / SPL;                                           \
    _Pragma("unroll 4") for (int cc = 0; cc < rps; ++cc) {                   \
      const int c = s * rps + cc;                                            \
      const uint4 wv =                                                       \
          *(const uint4*)((const T*)(Wp) + (size_t)c * DD + oc * VEC);       \
      fmaV<T>(acc, wv, (SRC)[c]);                                            \
    }                                                                        \
    _Pragma("unroll") for (int j = 0; j < VEC; ++j)                          \
        (PART)[s * DD + oc * VEC + j] = acc[j];                              \
  }

  // f = gelu(x @ W_b + b_b)
  GEMV_PART(W_b, xs, DIN, partA);
  __syncthreads();
  if (tid < DD) {
    float a = getv<T>(b_b, tid);
#pragma unroll
    for (int ss = 0; ss < SPL; ++ss) a += partA[ss * DD + tid];
    fs[tid] = gelu_tanh(a);
  }
  __syncthreads();

  // k = f @ Wk ; v = f @ Wv  (independent part buffers, one sync)
  GEMV_PART(Wk, fs, DD, partA);
  GEMV_PART(Wv, fs, DD, partB);
  __syncthreads();
  if (tid < DD) {
    float ak = 0.0f, av = 0.0f;
#pragma unroll
    for (int ss = 0; ss < SPL; ++ss) {
      ak += partA[ss * DD + tid];
      av += partB[ss * DD + tid];
    }
    kout[row * DD + tid] = ak;
    vout[row * DD + tid] = av;
  }

  // meta = sigmoid(f @ W_m + b_m): wave-parallel (wave 0), reads fs only
  if (tid < 64) {
    float a3[3];
#pragma unroll
    for (int j = 0; j < 3; ++j) {
      float pj = fs[tid] * getv<T>(W_m, tid * 3 + j) +
                 fs[tid + 64] * getv<T>(W_m, (tid + 64) * 3 + j);
      pj = rowsum16(pj);
      pj += __shfl_xor(pj, 16);
      pj += __shfl_xor(pj, 32);
      a3[j] = pj;
    }
    if (tid == 0) {
      scal4[row * 4 + 0] = 0.01f * sigmoidf(a3[0] + getv<T>(b_m, 0));
      scal4[row * 4 + 1] = sigmoidf(a3[1] + getv<T>(b_m, 1));
      scal4[row * 4 + 2] = 0.1f * sigmoidf(a3[2] + getv<T>(b_m, 2));
      scal4[row * 4 + 3] = 0.0f;
    }
  }

  // q & f kept only for t = T-1 (block-uniform branch -> syncthreads safe)
  if (t == TT - 1) {
    __syncthreads();
    GEMV_PART(Wq, fs, DD, partA);
    __syncthreads();
    if (tid < DD) {
      float aq = 0.0f;
#pragma unroll
      for (int ss = 0; ss < SPL; ++ss) aq += partA[ss * DD + tid];
      q_last[b * DD + tid] = aq;
      f_last[b * DD + tid] = fs[tid];
    }
  }
#undef GEMV_PART
}

__global__ __launch_bounds__(128) void k1_kern(
    const void* x, const void* W_b, const void* b_b, const void* Wk,
    const void* Wv, const void* Wq, const void* W_m, const void* b_m,
    float* kout, float* vout, float* scal4, float* q_last, float* f_last) {
  __shared__ int gcnt[2];
  {
    const int tid = threadIdx.x;
    const unsigned short* u = (const unsigned short*)x;
    int good = 0;
#pragma unroll
    for (int j = 0; j < 16; ++j) good += dtype_good(u, j * 128 + tid);
    float gf = (float)good;
    gf = rowsum16(gf);
    gf += __shfl_xor(gf, 16);
    gf += __shfl_xor(gf, 32);
    if ((tid & 63) == 0) gcnt[tid >> 6] = (int)(gf + 0.5f);
  }
  __syncthreads();
  const bool isbf16 = (gcnt[0] + gcnt[1] >= 1536);
  __syncthreads();  // gcnt re-use safety before body's LDS writes

  if (isbf16)
    k1_body<__hip_bfloat16>(x, W_b, b_b, Wk, Wv, Wq, W_m, b_m, kout, vout,
                            scal4, q_last, f_last);
  else
    k1_body<float>(x, W_b, b_b, Wk, Wv, Wq, W_m, b_m, kout, vout, scal4,
                   q_last, f_last);
}

// ---------------------------------------------------------------------------
// k2: the scan (r6 staging + r11 conflict-free fragment map, 1-ahead loop).
// REVERTED to the r11 optimum (144.72us e2e): r12's pinned depth-2 prefetch
// (146.3) and r14's algebraic lookahead (158.5) both regressed — per-step
// cost is NOT exposed-LDS-latency nor rowsum-chain; the simple schedule is
// the best of the three measured structures.
// ---------------------------------------------------------------------------
__global__ __launch_bounds__(64) void k2_scan(
    const float* __restrict__ kbuf, const float* __restrict__ vbuf,
    const float* __restrict__ scal, const float* __restrict__ q_last,
    float* __restrict__ m_last) {
  const int tid = threadIdx.x;         // 0..63
  const int g = tid & 15;
  const int cidx = tid >> 4;           // chain-in-block 0..3
  const int chain = blockIdx.x * 4 + cidx;
  const int b = chain >> 7;
  const int i = chain & 127;
  const int i0 = (blockIdx.x * 4) & 127;  // first chain's column

  __shared__ float kl[2][32 * DD];     // 2 x 16KB k chunks (32 t-rows each)
  __shared__ float vl[TT * 4];         // v[t][c] for this block's 4 chains
  __shared__ float4 scl[TT];           // (theta,eta,alpha,0) per t

  const float* kslice = kbuf + (size_t)b * TT * DD;
  const float* vslice = vbuf + (size_t)b * TT * DD;

  for (int idx = tid; idx < TT * 4; idx += 64)
    vl[idx] = vslice[(idx >> 2) * DD + i0 + (idx & 3)];
  const float4* sp4 = (const float4*)scal + b * TT;
  for (int idx = tid; idx < TT; idx += 64) scl[idx] = sp4[idx];

#define K2_GLL(CH, BUF)                                                      \
  {                                                                          \
    const float* gs = kslice + (CH) * 32 * DD + tid * 4;                     \
    _Pragma("unroll") for (int j = 0; j < 16; ++j)                           \
        gload_lds16(gs + j * 256, &kl[BUF][j * 256]);                        \
  }
  K2_GLL(0, 0);

  float4 Ma = {0, 0, 0, 0}, Mb = {0, 0, 0, 0};
  float4 Sa = {0, 0, 0, 0}, Sb = {0, 0, 0, 0};

#define K2_STEP(KA, KB, VV, SC)                                              \
  {                                                                          \
    float p = (Ma.x * KA.x + Ma.y * KA.y) + (Ma.z * KA.z + Ma.w * KA.w) +    \
              (Mb.x * KB.x + Mb.y * KB.y) + (Mb.z * KB.z + Mb.w * KB.w);     \
    p = rowsum16(p);                                                         \
    const float err = p - VV;                                                \
    const float c = SC.x * err;   /* theta * err */                          \
    const float et = SC.y;        /* eta */                                  \
    const float am = 1.0f - SC.z; /* 1 - alpha */                            \
    Sa.x = et * Sa.x - c * KA.x;  Ma.x = am * Ma.x + Sa.x;                   \
    Sa.y = et * Sa.y - c * KA.y;  Ma.y = am * Ma.y + Sa.y;                   \
    Sa.z = et * Sa.z - c * KA.z;  Ma.z = am * Ma.z + Sa.z;                   \
    Sa.w = et * Sa.w - c * KA.w;  Ma.w = am * Ma.w + Sa.w;                   \
    Sb.x = et * Sb.x - c * KB.x;  Mb.x = am * Mb.x + Sb.x;                   \
    Sb.y = et * Sb.y - c * KB.y;  Mb.y = am * Mb.y + Sb.y;                   \
    Sb.z = et * Sb.z - c * KB.z;  Mb.z = am * Mb.z + Sb.z;                   \
    Sb.w = et * Sb.w - c * KB.w;  Mb.w = am * Mb.w + Sb.w;                   \
  }

  for (int ch = 0; ch < 8; ++ch) {
    asm volatile("s_waitcnt vmcnt(0) lgkmcnt(0)" ::: "memory");
    if (ch < 7) K2_GLL(ch + 1, (ch + 1) & 1);

    const float* kc = &kl[ch & 1][0];
    const int tbase = ch * 32;

    // r11 conflict-free map: lane g owns [g*4,g*4+4) and [64+g*4,64+g*4+4)
    float4 ka = *(const float4*)(kc + g * 4);
    float4 kb = *(const float4*)(kc + 64 + g * 4);
    float vv = vl[tbase * 4 + cidx];
    float4 sc = scl[tbase];

#pragma unroll
    for (int tt = 0; tt < 32; ++tt) {
      float4 nka, nkb, nsc;
      float nv;
      if (tt < 31) {
        nka = *(const float4*)(kc + (tt + 1) * DD + g * 4);
        nkb = *(const float4*)(kc + (tt + 1) * DD + 64 + g * 4);
        nv = vl[(tbase + tt + 1) * 4 + cidx];
        nsc = scl[tbase + tt + 1];
      }
      K2_STEP(ka, kb, vv, sc);
      if (tt < 31) { ka = nka; kb = nkb; vv = nv; sc = nsc; }
    }
  }
#undef K2_STEP
#undef K2_GLL

  // q read uses the same fragment mapping
  const float* qb0 = q_last + b * DD;
  float4 qa = *(const float4*)(qb0 + g * 4);
  float4 qb = *(const float4*)(qb0 + 64 + g * 4);
  float p = (Ma.x * qa.x + Ma.y * qa.y) + (Ma.z * qa.z + Ma.w * qa.w) +
            (Mb.x * qb.x + Mb.y * qb.y) + (Mb.z * qb.z + Mb.w * qb.w);
  p = rowsum16(p);
  if (g == 0) m_last[b * DD + i] = p;
}

// ---------------------------------------------------------------------------
// k3: fused head (r10 vectorized structure, validated).
// 88 blocks (8 b x 11 j-chunks) x 256 threads.
// ---------------------------------------------------------------------------
template <typename T>
__device__ void k3_body(const float* f_last, const float* m_last,
                        const void* W_f, const void* b_f, const void* W1,
                        const void* b1, const void* g1, const void* be1,
                        const void* W2, const void* b2, void* out) {
  constexpr int VEC = (sizeof(T) == 2) ? 8 : 4;  // weights per 16B
  constexpr int OC = DD / VEC;                   // 16 / 32
  constexpr int SPL = 256 / OC;                  // 16 / 8
  const int b = blockIdx.x / 11;
  const int jc = blockIdx.x % 11;
  const int tid = threadIdx.x;        // 0..255
  const int oc = tid % OC, s = tid / OC;

  __shared__ float fm[2 * DD];
  __shared__ float part[2048];        // max(SPL*DD, SPL2*64) floats
  __shared__ float fused[DD];
  __shared__ float tmp[DD];
  __shared__ float h[DD];
  __shared__ float smu, srs;

  if (tid < 2 * DD)
    fm[tid] = (tid < DD) ? f_last[b * DD + tid] : m_last[b * DD + tid - DD];
  __syncthreads();

  float acc[VEC];

  // gate gemv: rows 2*DD=256, split SPL ways
  {
#pragma unroll
    for (int j = 0; j < VEC; ++j) acc[j] = 0.0f;
    constexpr int rps = 256 / SPL;  // 16 / 32
#pragma unroll 4
    for (int cc = 0; cc < rps; ++cc) {
      const int c = s * rps + cc;
      const uint4 wv =
          *(const uint4*)((const T*)W_f + (size_t)c * DD + oc * VEC);
      fmaV<T>(acc, wv, fm[c]);
    }
#pragma unroll
    for (int j = 0; j < VEC; ++j) part[s * DD + oc * VEC + j] = acc[j];
  }
  __syncthreads();
  if (tid < DD) {
    float a = getv<T>(b_f, tid);
#pragma unroll
    for (int ss = 0; ss < SPL; ++ss) a += part[ss * DD + tid];
    float gte = sigmoidf(a);
    fused[tid] = fm[tid] * gte + fm[DD + tid] * (1.0f - gte);
  }
  __syncthreads();

  // W1 gemv: rows DD=128
  {
#pragma unroll
    for (int j = 0; j < VEC; ++j) acc[j] = 0.0f;
    constexpr int rps = DD / SPL;  // 8 / 16
#pragma unroll 4
    for (int cc = 0; cc < rps; ++cc) {
      const int c = s * rps + cc;
      const uint4 wv =
          *(const uint4*)((const T*)W1 + (size_t)c * DD + oc * VEC);
      fmaV<T>(acc, wv, fused[c]);
    }
#pragma unroll
    for (int j = 0; j < VEC; ++j) part[s * DD + oc * VEC + j] = acc[j];
  }
  __syncthreads();
  if (tid < DD) {
    float a = getv<T>(b1, tid);
#pragma unroll
    for (int ss = 0; ss < SPL; ++ss) a += part[ss * DD + tid];
    tmp[tid] = a;
  }
  __syncthreads();

  // LN stats: wave-parallel reduce over 128 elems (first wave only)
  if (tid < 64) {
    float x0 = tmp[tid], x1 = tmp[tid + 64];
    float sm = x0 + x1;
    float sq = x0 * x0 + x1 * x1;
    sm = rowsum16(sm);
    sq = rowsum16(sq);
    sm += __shfl_xor(sm, 16); sq += __shfl_xor(sq, 16);
    sm += __shfl_xor(sm, 32); sq += __shfl_xor(sq, 32);
    if (tid == 0) {
      float mu = sm / (float)DD;
      smu = mu;
      srs = rsqrtf(sq / (float)DD - mu * mu + 1e-5f);
    }
  }
  __syncthreads();

  if (tid < DD)
    h[tid] = gelu_tanh((tmp[tid] - smu) * srs * getv<T>(g1, tid) +
                       getv<T>(be1, tid));
  __syncthreads();

  // W2 chunk gemv: 64 j's tiled as (jv x VEC), c split SPL2 ways
  {
    constexpr int NJ = 64 / VEC;     // 8 / 16
    constexpr int SPL2 = 256 / NJ;   // 32 / 16
    constexpr int rps2 = DD / SPL2;  // 4 / 8
    const int jv = tid % NJ, s2 = tid / NJ;
    const int jbase = jc * 64 + jv * VEC;
#pragma unroll
    for (int j = 0; j < VEC; ++j) acc[j] = 0.0f;
    if (jbase < 672) {  // jc=10 tail guard (uniform per thread)
#pragma unroll
      for (int cc = 0; cc < rps2; ++cc) {
        const int c = s2 * rps2 + cc;
        const uint4 wv = *(const uint4*)((const T*)W2 + (size_t)c * 672 + jbase);
        fmaV<T>(acc, wv, h[c]);
      }
    }
#pragma unroll
    for (int j = 0; j < VEC; ++j) part[s2 * 64 + jv * VEC + j] = acc[j];
    __syncthreads();

    const int j = jc * 64 + tid;
    if (tid < 64 && j < 672) {
      float r = getv<T>(b2, j);
#pragma unroll
      for (int ss = 0; ss < SPL2; ++ss) r += part[ss * 64 + tid];
      if (sizeof(T) == 2)
        ((__hip_bfloat16*)out)[b * 672 + j] = __float2bfloat16(r);
      else
        ((float*)out)[b * 672 + j] = r;
    }
  }
}

__global__ __launch_bounds__(256) void k3_kern(
    const void* x, const float* f_last, const float* m_last, const void* W_f,
    const void* b_f, const void* W1, const void* b1, const void* g1,
    const void* be1, const void* W2, const void* b2, void* out) {
  __shared__ int gcnt[4];
  {
    const int tid = threadIdx.x;
    const unsigned short* u = (const unsigned short*)x;
    int good = 0;
#pragma unroll
    for (int j = 0; j < 8; ++j) good += dtype_good(u, j * 256 + tid);
    float gf = (float)good;
    gf = rowsum16(gf);
    gf += __shfl_xor(gf, 16);
    gf += __shfl_xor(gf, 32);
    if ((tid & 63) == 0) gcnt[tid >> 6] = (int)(gf + 0.5f);
  }
  __syncthreads();
  const bool isbf16 = (gcnt[0] + gcnt[1] + gcnt[2] + gcnt[3] >= 1536);
  __syncthreads();

  if (isbf16)
    k3_body<__hip_bfloat16>(f_last, m_last, W_f, b_f, W1, b1, g1, be1, W2, b2,
                            out);
  else
    k3_body<float>(f_last, m_last, W_f, b_f, W1, b1, g1, be1, W2, b2, out);
}

// ---------------------------------------------------------------------------
extern "C" void kernel_launch(void* const* d_in, const int* in_sizes, int n_in,
                              void* d_out, int out_size, void* d_ws,
                              size_t ws_size, hipStream_t stream) {
  const void* x   = d_in[0];
  const void* W_b = d_in[1];
  const void* b_b = d_in[2];
  const void* Wk  = d_in[3];
  const void* Wv  = d_in[4];
  const void* Wq  = d_in[5];
  const void* W_m = d_in[6];
  const void* b_m = d_in[7];
  const void* W_f = d_in[8];
  const void* b_f = d_in[9];
  const void* W1  = d_in[10];
  const void* b1  = d_in[11];
  const void* g1  = d_in[12];
  const void* be1 = d_in[13];
  const void* W2  = d_in[14];
  const void* b2  = d_in[15];

  float* w = (float*)d_ws;
  float* kbuf   = w;                    // 262144
  float* vbuf   = w + 262144;           // 262144
  float* scal4  = w + 524288;           // 8192  (theta,eta,alpha,0) per (b,t)
  float* q_last = w + 532480;           // 1024
  float* f_last = w + 533504;           // 1024
  float* m_last = w + 534528;           // 1024

  k1_kern<<<BB * TT, 128, 0, stream>>>(x, W_b, b_b, Wk, Wv, Wq, W_m, b_m,
                                       kbuf, vbuf, scal4, q_last, f_last);
  k2_scan<<<256, 64, 0, stream>>>(kbuf, vbuf, scal4, q_last, m_last);
  k3_kern<<<88, 256, 0, stream>>>(x, f_last, m_last, W_f, b_f, W1, b1, g1,
                                  be1, W2, b2, d_out);
}